// Round 1
// baseline (464.631 us; speedup 1.0000x reference)
//
#include <hip/hip_runtime.h>
#include <cstdint>

static constexpr int cB = 128;
static constexpr int cN = 196;
static constexpr int cD = 768;
static constexpr int cNN = cN * cN;      // 38416
static constexpr int cND = cN * cD;      // 150528
static constexpr float cEPS = 1e-6f;

// ---------------------------------------------------------------------------
// K1: global max of motion and saliency (jnp.max over the WHOLE array)
// ---------------------------------------------------------------------------
__global__ void k_maxes(const float* __restrict__ mo, const float* __restrict__ sa,
                        float* __restrict__ wsmax) {
    __shared__ float redm[4], reds[4];
    int t = threadIdx.x;
    float mm = -1e30f, ms = -1e30f;
    for (int i = t; i < cB * cN; i += 256) {
        mm = fmaxf(mm, mo[i]);
        ms = fmaxf(ms, sa[i]);
    }
    for (int off = 32; off; off >>= 1) {
        mm = fmaxf(mm, __shfl_down(mm, off));
        ms = fmaxf(ms, __shfl_down(ms, off));
    }
    if ((t & 63) == 0) { redm[t >> 6] = mm; reds[t >> 6] = ms; }
    __syncthreads();
    if (t == 0) {
        float a = redm[0], b = reds[0];
        for (int w = 1; w < 4; w++) { a = fmaxf(a, redm[w]); b = fmaxf(b, reds[w]); }
        wsmax[0] = a; wsmax[1] = b;
    }
}

// ---------------------------------------------------------------------------
// K2: importance per batch (note: compression_ratio coefficient is exactly 0)
// ---------------------------------------------------------------------------
__global__ void k_importance(const float* __restrict__ mo, const float* __restrict__ sa,
                             const float* __restrict__ wsmax,
                             float* __restrict__ out_imp, float* __restrict__ ws_imp) {
    int b = blockIdx.x, t = threadIdx.x;
    __shared__ float lo_s[4], hi_s[4], LOHI[2];
    float Minv = 1.0f / (wsmax[0] + cEPS);
    float Sinv = 1.0f / (wsmax[1] + cEPS);
    float v = 0.f, lo = 1e30f, hi = -1e30f;
    if (t < cN) {
        v = 0.5f * mo[b * cN + t] * Minv + 0.5f * sa[b * cN + t] * Sinv;
        lo = v; hi = v;
    }
    for (int off = 32; off; off >>= 1) {
        lo = fminf(lo, __shfl_down(lo, off));
        hi = fmaxf(hi, __shfl_down(hi, off));
    }
    if ((t & 63) == 0) { lo_s[t >> 6] = lo; hi_s[t >> 6] = hi; }
    __syncthreads();
    if (t == 0) {
        float l = lo_s[0], h = hi_s[0];
        for (int w = 1; w < 4; w++) { l = fminf(l, lo_s[w]); h = fmaxf(h, hi_s[w]); }
        LOHI[0] = l; LOHI[1] = h;
    }
    __syncthreads();
    if (t < cN) {
        float imp = (v - LOHI[0]) / (LOHI[1] - LOHI[0] + cEPS);
        out_imp[b * cN + t] = imp;
        ws_imp[b * cN + t] = imp;
    }
}

// ---------------------------------------------------------------------------
// K3: inverse token norms (F.normalize eps=1e-12). One wave per token.
// ---------------------------------------------------------------------------
__global__ void k_invnorm(const float* __restrict__ tok, float* __restrict__ invn) {
    int wid = blockIdx.x * 4 + (threadIdx.x >> 6);   // token index
    int lane = threadIdx.x & 63;
    if (wid >= cB * cN) return;
    const float4* p4 = (const float4*)(tok + (size_t)wid * cD);  // 192 float4s
    float s = 0.f;
    #pragma unroll
    for (int r = 0; r < 3; r++) {
        float4 v = p4[lane + 64 * r];
        s += v.x * v.x + v.y * v.y + v.z * v.z + v.w * v.w;
    }
    for (int off = 32; off; off >>= 1) s += __shfl_down(s, off);
    if (lane == 0) invn[wid] = 1.0f / fmaxf(sqrtf(s), 1e-12f);
}

// ---------------------------------------------------------------------------
// K4: sim = tn . tn^T per batch, diagonal zeroed.
// 64x64 tile per block, 16x16 threads x 4x4 micro-tile, K chunks of 32 in LDS.
// LDS stored k-major with row-stride 68 (pad 4 keeps float4 alignment).
// ---------------------------------------------------------------------------
__global__ __launch_bounds__(256) void k_sim(const float* __restrict__ tok,
                                             const float* __restrict__ invn,
                                             float* __restrict__ out_sim) {
    __shared__ float As[32 * 68];
    __shared__ float Bs[32 * 68];
    int b = blockIdx.z;
    int rb = blockIdx.y * 64, cb = blockIdx.x * 64;
    int t = threadIdx.x;
    int kq = t & 7, rr = t >> 3;          // loader mapping: 8 thr/row-chunk, 32 rows
    int tx = t & 15, ty = t >> 4;         // compute mapping

    float acc[4][4];
    #pragma unroll
    for (int i = 0; i < 4; i++)
        #pragma unroll
        for (int j = 0; j < 4; j++) acc[i][j] = 0.f;

    const float* tb = tok + (size_t)b * cND;
    const float* ib = invn + b * cN;

    for (int k0 = 0; k0 < cD; k0 += 32) {
        #pragma unroll
        for (int half = 0; half < 2; half++) {
            int row = rr + 32 * half;
            // A tile
            int gr = rb + row;
            float4 v = make_float4(0.f, 0.f, 0.f, 0.f);
            if (gr < cN) {
                v = *(const float4*)(tb + (size_t)gr * cD + k0 + 4 * kq);
                float iv = ib[gr];
                v.x *= iv; v.y *= iv; v.z *= iv; v.w *= iv;
            }
            As[(4 * kq + 0) * 68 + row] = v.x;
            As[(4 * kq + 1) * 68 + row] = v.y;
            As[(4 * kq + 2) * 68 + row] = v.z;
            As[(4 * kq + 3) * 68 + row] = v.w;
            // B tile
            int gc = cb + row;
            float4 u = make_float4(0.f, 0.f, 0.f, 0.f);
            if (gc < cN) {
                u = *(const float4*)(tb + (size_t)gc * cD + k0 + 4 * kq);
                float iv = ib[gc];
                u.x *= iv; u.y *= iv; u.z *= iv; u.w *= iv;
            }
            Bs[(4 * kq + 0) * 68 + row] = u.x;
            Bs[(4 * kq + 1) * 68 + row] = u.y;
            Bs[(4 * kq + 2) * 68 + row] = u.z;
            Bs[(4 * kq + 3) * 68 + row] = u.w;
        }
        __syncthreads();
        #pragma unroll
        for (int k = 0; k < 32; k++) {
            float4 a = *(const float4*)&As[k * 68 + 4 * ty];
            float4 bb = *(const float4*)&Bs[k * 68 + 4 * tx];
            acc[0][0] += a.x * bb.x; acc[0][1] += a.x * bb.y; acc[0][2] += a.x * bb.z; acc[0][3] += a.x * bb.w;
            acc[1][0] += a.y * bb.x; acc[1][1] += a.y * bb.y; acc[1][2] += a.y * bb.z; acc[1][3] += a.y * bb.w;
            acc[2][0] += a.z * bb.x; acc[2][1] += a.z * bb.y; acc[2][2] += a.z * bb.z; acc[2][3] += a.z * bb.w;
            acc[3][0] += a.w * bb.x; acc[3][1] += a.w * bb.y; acc[3][2] += a.w * bb.z; acc[3][3] += a.w * bb.w;
        }
        __syncthreads();
    }

    float* so = out_sim + (size_t)b * cNN;
    #pragma unroll
    for (int i = 0; i < 4; i++) {
        int R = rb + 4 * ty + i;
        if (R >= cN) continue;
        #pragma unroll
        for (int j = 0; j < 4; j++) {
            int C = cb + 4 * tx + j;
            if (C < cN) so[(size_t)R * cN + C] = (R == C) ? 0.f : acc[i][j];
        }
    }
}

// ---------------------------------------------------------------------------
// K5: grouping. One block per batch. Builds per-thread incoming-edge bitmasks
// (adjT) in registers from sim columns; fast path when there are no edges
// (always, for random tokens: cos-sim sigma ~ 0.036 << 0.9); general path is
// a faithful sequential-root BFS matching the reference semantics.
// ---------------------------------------------------------------------------
__global__ __launch_bounds__(256) void k_group(const float* __restrict__ sim,
                                               const float* __restrict__ ws_imp,
                                               float* __restrict__ out_gids,
                                               float* __restrict__ ws_w,
                                               int* __restrict__ ws_flag,
                                               int* __restrict__ ws_gids) {
    int b = blockIdx.x, t = threadIdx.x;
    __shared__ float impL[cN];
    __shared__ unsigned long long reachw[4], assignedw[4], edge_s[4];
    __shared__ int flag;
    __shared__ int gidsL[cN];
    __shared__ float denomL[cN];

    if (t < cN) impL[t] = ws_imp[b * cN + t];
    __syncthreads();

    // adjT masks: bit n of (m0..m3) = edge n -> t exists
    unsigned long long m0 = 0, m1 = 0, m2 = 0, m3 = 0;
    if (t < cN) {
        const float* srow = sim + (size_t)b * cNN;
        for (int n = 0; n < cN; n++) {
            float sv = srow[(size_t)n * cN + t];   // coalesced across t
            if (sv > 0.9f && impL[n] < 0.5f) {
                if (n < 64)       m0 |= 1ull << n;
                else if (n < 128) m1 |= 1ull << (n - 64);
                else if (n < 192) m2 |= 1ull << (n - 128);
                else              m3 |= 1ull << (n - 192);
            }
        }
    }
    unsigned long long anym = m0 | m1 | m2 | m3;
    unsigned long long bal = __ballot(anym != 0ull);
    if ((t & 63) == 0) edge_s[t >> 6] = bal;
    __syncthreads();
    bool has_edges = (edge_s[0] | edge_s[1] | edge_s[2] | edge_s[3]) != 0ull;

    if (!has_edges) {
        // every token its own group, gid == token index
        if (t < cN) {
            float imp = impL[t];
            ws_w[b * cN + t] = imp / (imp + cEPS);
            ws_gids[b * cN + t] = t;
            out_gids[b * cN + t] = (float)t;
        }
        if (t == 0) ws_flag[b] = 1;
        return;
    }

    // ---- general sequential-root BFS (faithful to reference) ----
    if (t < 4) assignedw[t] = 0ull;
    if (t < cN) { gidsL[t] = 0; denomL[t] = 0.f; }
    __syncthreads();
    int gid = 0;
    int wrd_t = t >> 6, bit_t = t & 63;
    for (int r = 0; r < cN; r++) {
        if ((assignedw[r >> 6] >> (r & 63)) & 1ull) continue;   // uniform
        if (t < 4) reachw[t] = (t == (r >> 6)) ? (1ull << (r & 63)) : 0ull;
        __syncthreads();
        int changed = 1;
        while (changed) {
            unsigned long long hit = (m0 & reachw[0]) | (m1 & reachw[1]) |
                                     (m2 & reachw[2]) | (m3 & reachw[3]);
            bool inre = (t < cN) && ((reachw[wrd_t] >> bit_t) & 1ull);
            bool unass = (t < cN) && !((assignedw[wrd_t] >> bit_t) & 1ull);
            bool p = inre || (hit != 0ull && unass);
            unsigned long long nw = __ballot(p);
            __syncthreads();                       // all reads of reachw done
            if (t == 0) flag = 0;
            __syncthreads();
            if ((t & 63) == 0) {
                if (nw != reachw[t >> 6]) flag = 1;
                reachw[t >> 6] = nw;
            }
            __syncthreads();
            changed = flag;
        }
        if ((t < cN) && ((reachw[wrd_t] >> bit_t) & 1ull)) gidsL[t] = gid;
        if (t < 4) assignedw[t] |= reachw[t];
        gid++;
        __syncthreads();
    }
    if (t < cN) atomicAdd(&denomL[gidsL[t]], impL[t]);
    __syncthreads();
    if (t < cN) {
        int g = gidsL[t];
        ws_w[b * cN + t] = impL[t] / (denomL[g] + cEPS);
        ws_gids[b * cN + t] = g;
        out_gids[b * cN + t] = (float)g;
    }
    if (t == 0) ws_flag[b] = 0;
}

// ---------------------------------------------------------------------------
// K6: merged tokens. Fast path (identity grouping): direct scaled copy.
// General path: deterministic gather-sum over the 196 tokens.
// ---------------------------------------------------------------------------
__global__ void k_merge(const float* __restrict__ tok, const float* __restrict__ ws_w,
                        const int* __restrict__ ws_flag, const int* __restrict__ ws_gids,
                        float* __restrict__ out) {
    int b = blockIdx.y;
    int idx = blockIdx.x * 256 + threadIdx.x;     // < cND, blocks never straddle batches
    int n = idx / cD, d = idx - n * cD;
    size_t e = (size_t)b * cND + idx;
    if (ws_flag[b]) {
        out[e] = tok[e] * ws_w[b * cN + n];
    } else {
        float acc = 0.f;
        const int* g = ws_gids + b * cN;
        const float* w = ws_w + b * cN;
        const float* tb = tok + (size_t)b * cND + d;
        for (int j = 0; j < cN; j++)
            if (g[j] == n) acc += tb[(size_t)j * cD] * w[j];
        out[e] = acc;
    }
}

// ---------------------------------------------------------------------------
extern "C" void kernel_launch(void* const* d_in, const int* in_sizes, int n_in,
                              void* d_out, int out_size, void* d_ws, size_t ws_size,
                              hipStream_t stream) {
    const float* tok = (const float*)d_in[0];
    const float* mo  = (const float*)d_in[1];
    const float* sa  = (const float*)d_in[2];
    // d_in[3] (compression_ratio) is multiplied by (1-0.5-0.5)==0 in the ref.

    float* out = (float*)d_out;
    float* out_merged = out;                                  // B*N*D
    float* out_sim    = out + (size_t)cB * cND;               // B*N*N
    float* out_imp    = out_sim + (size_t)cB * cNN;           // B*N
    float* out_gids   = out_imp + (size_t)cB * cN;            // B*N (as float)

    float* wsf     = (float*)d_ws;
    float* ws_max  = wsf;                   // 2 floats
    float* ws_imp  = wsf + 64;              // B*N
    float* ws_invn = ws_imp + cB * cN;      // B*N
    float* ws_w    = ws_invn + cB * cN;     // B*N
    int*   ws_flag = (int*)(ws_w + cB * cN);// B ints
    int*   ws_gids = ws_flag + cB;          // B*N ints

    k_maxes<<<1, 256, 0, stream>>>(mo, sa, ws_max);
    k_importance<<<cB, 256, 0, stream>>>(mo, sa, ws_max, out_imp, ws_imp);
    k_invnorm<<<(cB * cN + 3) / 4, 256, 0, stream>>>(tok, ws_invn);
    k_sim<<<dim3(4, 4, cB), 256, 0, stream>>>(tok, ws_invn, out_sim);
    k_group<<<cB, 256, 0, stream>>>(out_sim, ws_imp, out_gids, ws_w, ws_flag, ws_gids);
    k_merge<<<dim3(cND / 256, cB), 256, 0, stream>>>(tok, ws_w, ws_flag, ws_gids, out_merged);
}

// Round 2
// 295.508 us; speedup vs baseline: 1.5723x; 1.5723x over previous
//
#include <hip/hip_runtime.h>
#include <cstdint>

static constexpr int cB = 128;
static constexpr int cN = 196;
static constexpr int cD = 768;
static constexpr int cNN = cN * cN;      // 38416
static constexpr int cND = cN * cD;      // 150528
static constexpr float cEPS = 1e-6f;
static constexpr size_t cBND = (size_t)cB * cN * cD;   // 19,267,584 elements

typedef __attribute__((ext_vector_type(8))) short short8;
typedef __attribute__((ext_vector_type(4))) float f32x4;

__device__ __forceinline__ unsigned short bf16_rne(float x) {
    unsigned u = __builtin_bit_cast(unsigned, x);
    u += 0x7FFFu + ((u >> 16) & 1u);
    return (unsigned short)(u >> 16);
}
__device__ __forceinline__ float bf16_to_f(unsigned short h) {
    return __builtin_bit_cast(float, (unsigned)h << 16);
}

// ---------------------------------------------------------------------------
// K1: global max of motion and saliency (jnp.max over the WHOLE array)
// ---------------------------------------------------------------------------
__global__ void k_maxes(const float* __restrict__ mo, const float* __restrict__ sa,
                        float* __restrict__ wsmax) {
    __shared__ float redm[16], reds[16];
    int t = threadIdx.x;
    float mm = -1e30f, ms = -1e30f;
    for (int i = t; i < cB * cN; i += 1024) {
        mm = fmaxf(mm, mo[i]);
        ms = fmaxf(ms, sa[i]);
    }
    for (int off = 32; off; off >>= 1) {
        mm = fmaxf(mm, __shfl_down(mm, off));
        ms = fmaxf(ms, __shfl_down(ms, off));
    }
    if ((t & 63) == 0) { redm[t >> 6] = mm; reds[t >> 6] = ms; }
    __syncthreads();
    if (t == 0) {
        float a = redm[0], b = reds[0];
        for (int w = 1; w < 16; w++) { a = fmaxf(a, redm[w]); b = fmaxf(b, reds[w]); }
        wsmax[0] = a; wsmax[1] = b;
    }
}

// ---------------------------------------------------------------------------
// K2: importance per batch (compression_ratio coefficient is exactly 0)
// ---------------------------------------------------------------------------
__global__ void k_importance(const float* __restrict__ mo, const float* __restrict__ sa,
                             const float* __restrict__ wsmax,
                             float* __restrict__ out_imp, float* __restrict__ ws_imp) {
    int b = blockIdx.x, t = threadIdx.x;
    __shared__ float lo_s[4], hi_s[4], LOHI[2];
    float Minv = 1.0f / (wsmax[0] + cEPS);
    float Sinv = 1.0f / (wsmax[1] + cEPS);
    float v = 0.f, lo = 1e30f, hi = -1e30f;
    if (t < cN) {
        v = 0.5f * mo[b * cN + t] * Minv + 0.5f * sa[b * cN + t] * Sinv;
        lo = v; hi = v;
    }
    for (int off = 32; off; off >>= 1) {
        lo = fminf(lo, __shfl_down(lo, off));
        hi = fmaxf(hi, __shfl_down(hi, off));
    }
    if ((t & 63) == 0) { lo_s[t >> 6] = lo; hi_s[t >> 6] = hi; }
    __syncthreads();
    if (t == 0) {
        float l = lo_s[0], h = hi_s[0];
        for (int w = 1; w < 4; w++) { l = fminf(l, lo_s[w]); h = fmaxf(h, hi_s[w]); }
        LOHI[0] = l; LOHI[1] = h;
    }
    __syncthreads();
    if (t < cN) {
        float imp = (v - LOHI[0]) / (LOHI[1] - LOHI[0] + cEPS);
        out_imp[b * cN + t] = imp;
        ws_imp[b * cN + t] = imp;
    }
}

// ---------------------------------------------------------------------------
// K3: normalize each token (F.normalize eps=1e-12) and split to bf16 hi/lo
// planes. One wave per token; 12 elements/lane. hi plane at hiP[0..BND),
// lo plane at hiP[BND..2BND) (ushort units). Planes live in the `merged`
// output region, which is only written by k_merge at the very end.
// ---------------------------------------------------------------------------
__global__ void k_convert(const float* __restrict__ tok, unsigned short* __restrict__ hiP) {
    int wid = blockIdx.x * 4 + (threadIdx.x >> 6);   // token index
    int lane = threadIdx.x & 63;
    if (wid >= cB * cN) return;
    const float4* p4 = (const float4*)(tok + (size_t)wid * cD);  // 192 float4s
    float4 v[3];
    float s = 0.f;
    #pragma unroll
    for (int r = 0; r < 3; r++) {
        v[r] = p4[lane + 64 * r];
        s += v[r].x * v[r].x + v[r].y * v[r].y + v[r].z * v[r].z + v[r].w * v[r].w;
    }
    #pragma unroll
    for (int off = 32; off; off >>= 1) s += __shfl_xor(s, off);
    float inv = 1.0f / fmaxf(sqrtf(s), 1e-12f);
    ushort4* hp = (ushort4*)(hiP + (size_t)wid * cD);
    ushort4* lp = (ushort4*)(hiP + cBND + (size_t)wid * cD);
    #pragma unroll
    for (int r = 0; r < 3; r++) {
        float x0 = v[r].x * inv, x1 = v[r].y * inv, x2 = v[r].z * inv, x3 = v[r].w * inv;
        ushort4 h, l;
        h.x = bf16_rne(x0); l.x = bf16_rne(x0 - bf16_to_f(h.x));
        h.y = bf16_rne(x1); l.y = bf16_rne(x1 - bf16_to_f(h.y));
        h.z = bf16_rne(x2); l.z = bf16_rne(x2 - bf16_to_f(h.z));
        h.w = bf16_rne(x3); l.w = bf16_rne(x3 - bf16_to_f(h.w));
        hp[lane + 64 * r] = h;
        lp[lane + 64 * r] = l;
    }
}

// ---------------------------------------------------------------------------
// K4: sim = tn . tn^T per batch via split-bf16 MFMA (hi*hi + lo*hi + hi*lo).
// 128x128 tile/block, 4 waves each computing 32 rows x 128 cols via
// mfma_f32_16x16x32_bf16. LDS row stride 40 bf16 (80B) -> only free 2-way
// bank aliasing on ds_read_b128 frag loads. 1-D grid, XCD-swizzled so all 4
// tiles of a batch share one XCD's L2.
// ---------------------------------------------------------------------------
__global__ __launch_bounds__(256, 3) void k_sim(const unsigned short* __restrict__ hiP,
                                                float* __restrict__ out_sim) {
    __shared__ unsigned short sA_hi[128 * 40];
    __shared__ unsigned short sA_lo[128 * 40];
    __shared__ unsigned short sB_hi[128 * 40];
    __shared__ unsigned short sB_lo[128 * 40];

    int bid = blockIdx.x;            // 0..511
    int xcd = bid & 7;
    int lin = bid >> 3;              // 0..63
    int b   = xcd + 8 * (lin >> 2);  // 0..127 (all 4 tiles of b -> same XCD)
    int tile = lin & 3;
    int rb = (tile >> 1) * 128, cb = (tile & 1) * 128;

    int t = threadIdx.x;
    int w = t >> 6, lane = t & 63;
    int lr = lane & 15, kf = (lane >> 4) * 8;    // frag row/col and k-offset

    f32x4 acc[2][8];
    #pragma unroll
    for (int i = 0; i < 2; i++)
        #pragma unroll
        for (int j = 0; j < 8; j++) acc[i][j] = (f32x4){0.f, 0.f, 0.f, 0.f};

    const size_t bN = (size_t)b * cN;
    const unsigned short* loP = hiP + cBND;

    int srow = t >> 2;          // staging: 0..63
    int q = t & 3;              // 16B quarter of a 64B row-chunk

    for (int k0 = 0; k0 < cD; k0 += 32) {
        // ---- stage A/B hi+lo tiles (128 rows x 32 k, bf16) ----
        #pragma unroll
        for (int p = 0; p < 2; ++p) {
            int row = srow + 64 * p;
            size_t koff = (size_t)k0 + 8 * q;
            uint4 zz = make_uint4(0u, 0u, 0u, 0u);
            uint4 vah = zz, val = zz, vbh = zz, vbl = zz;
            int gr = rb + row;
            if (gr < cN) {
                const unsigned short* base = hiP + (bN + gr) * cD + koff;
                vah = *(const uint4*)base;
                val = *(const uint4*)(loP + (bN + gr) * cD + koff);
            }
            int gc = cb + row;
            if (gc < cN) {
                const unsigned short* base = hiP + (bN + gc) * cD + koff;
                vbh = *(const uint4*)base;
                vbl = *(const uint4*)(loP + (bN + gc) * cD + koff);
            }
            *(uint4*)&sA_hi[row * 40 + 8 * q] = vah;
            *(uint4*)&sA_lo[row * 40 + 8 * q] = val;
            *(uint4*)&sB_hi[row * 40 + 8 * q] = vbh;
            *(uint4*)&sB_lo[row * 40 + 8 * q] = vbl;
        }
        __syncthreads();

        // ---- MFMA: wave w covers rows [32w, 32w+32), all 128 cols ----
        short8 a_h[2], a_l[2];
        #pragma unroll
        for (int rg = 0; rg < 2; rg++) {
            int row = 32 * w + 16 * rg + lr;
            a_h[rg] = *(const short8*)&sA_hi[row * 40 + kf];
            a_l[rg] = *(const short8*)&sA_lo[row * 40 + kf];
        }
        #pragma unroll
        for (int cg = 0; cg < 8; cg++) {
            int col = 16 * cg + lr;
            short8 b_h = *(const short8*)&sB_hi[col * 40 + kf];
            short8 b_l = *(const short8*)&sB_lo[col * 40 + kf];
            #pragma unroll
            for (int rg = 0; rg < 2; rg++) {
                acc[rg][cg] = __builtin_amdgcn_mfma_f32_16x16x32_bf16(a_h[rg], b_h, acc[rg][cg], 0, 0, 0);
                acc[rg][cg] = __builtin_amdgcn_mfma_f32_16x16x32_bf16(a_l[rg], b_h, acc[rg][cg], 0, 0, 0);
                acc[rg][cg] = __builtin_amdgcn_mfma_f32_16x16x32_bf16(a_h[rg], b_l, acc[rg][cg], 0, 0, 0);
            }
        }
        __syncthreads();
    }

    // ---- epilogue: C/D layout col=lane&15, row=(lane>>4)*4+reg ----
    float* so = out_sim + (size_t)b * cNN;
    #pragma unroll
    for (int rg = 0; rg < 2; rg++) {
        int Rbase = rb + 32 * w + 16 * rg + (lane >> 4) * 4;
        #pragma unroll
        for (int cg = 0; cg < 8; cg++) {
            int C = cb + 16 * cg + lr;
            if (C >= cN) continue;
            #pragma unroll
            for (int i = 0; i < 4; i++) {
                int R = Rbase + i;
                if (R < cN) so[(size_t)R * cN + C] = (R == C) ? 0.f : acc[rg][cg][i];
            }
        }
    }
}

// ---------------------------------------------------------------------------
// K5: grouping. One block per batch; fast path when no edges (always, for
// random tokens: cos-sim sigma ~0.036 << 0.9); general path = faithful
// sequential-root BFS matching reference semantics.
// ---------------------------------------------------------------------------
__global__ __launch_bounds__(256) void k_group(const float* __restrict__ sim,
                                               const float* __restrict__ ws_imp,
                                               float* __restrict__ out_gids,
                                               float* __restrict__ ws_w,
                                               int* __restrict__ ws_flag,
                                               int* __restrict__ ws_gids) {
    int b = blockIdx.x, t = threadIdx.x;
    __shared__ float impL[cN];
    __shared__ unsigned long long reachw[4], assignedw[4], edge_s[4];
    __shared__ int flag;
    __shared__ int gidsL[cN];
    __shared__ float denomL[cN];

    if (t < cN) impL[t] = ws_imp[b * cN + t];
    __syncthreads();

    unsigned long long m0 = 0, m1 = 0, m2 = 0, m3 = 0;
    if (t < cN) {
        const float* srow = sim + (size_t)b * cNN;
        for (int n = 0; n < cN; n++) {
            float sv = srow[(size_t)n * cN + t];   // coalesced across t
            if (sv > 0.9f && impL[n] < 0.5f) {
                if (n < 64)       m0 |= 1ull << n;
                else if (n < 128) m1 |= 1ull << (n - 64);
                else if (n < 192) m2 |= 1ull << (n - 128);
                else              m3 |= 1ull << (n - 192);
            }
        }
    }
    unsigned long long anym = m0 | m1 | m2 | m3;
    unsigned long long bal = __ballot(anym != 0ull);
    if ((t & 63) == 0) edge_s[t >> 6] = bal;
    __syncthreads();
    bool has_edges = (edge_s[0] | edge_s[1] | edge_s[2] | edge_s[3]) != 0ull;

    if (!has_edges) {
        if (t < cN) {
            float imp = impL[t];
            ws_w[b * cN + t] = imp / (imp + cEPS);
            ws_gids[b * cN + t] = t;
            out_gids[b * cN + t] = (float)t;
        }
        if (t == 0) ws_flag[b] = 1;
        return;
    }

    if (t < 4) assignedw[t] = 0ull;
    if (t < cN) { gidsL[t] = 0; denomL[t] = 0.f; }
    __syncthreads();
    int gid = 0;
    int wrd_t = t >> 6, bit_t = t & 63;
    for (int r = 0; r < cN; r++) {
        if ((assignedw[r >> 6] >> (r & 63)) & 1ull) continue;   // uniform
        if (t < 4) reachw[t] = (t == (r >> 6)) ? (1ull << (r & 63)) : 0ull;
        __syncthreads();
        int changed = 1;
        while (changed) {
            unsigned long long hit = (m0 & reachw[0]) | (m1 & reachw[1]) |
                                     (m2 & reachw[2]) | (m3 & reachw[3]);
            bool inre = (t < cN) && ((reachw[wrd_t] >> bit_t) & 1ull);
            bool unass = (t < cN) && !((assignedw[wrd_t] >> bit_t) & 1ull);
            bool p = inre || (hit != 0ull && unass);
            unsigned long long nw = __ballot(p);
            __syncthreads();
            if (t == 0) flag = 0;
            __syncthreads();
            if ((t & 63) == 0) {
                if (nw != reachw[t >> 6]) flag = 1;
                reachw[t >> 6] = nw;
            }
            __syncthreads();
            changed = flag;
        }
        if ((t < cN) && ((reachw[wrd_t] >> bit_t) & 1ull)) gidsL[t] = gid;
        if (t < 4) assignedw[t] |= reachw[t];
        gid++;
        __syncthreads();
    }
    if (t < cN) atomicAdd(&denomL[gidsL[t]], impL[t]);
    __syncthreads();
    if (t < cN) {
        int g = gidsL[t];
        ws_w[b * cN + t] = impL[t] / (denomL[g] + cEPS);
        ws_gids[b * cN + t] = g;
        out_gids[b * cN + t] = (float)g;
    }
    if (t == 0) ws_flag[b] = 0;
}

// ---------------------------------------------------------------------------
// K6: merged tokens (float4). Fast path: scaled copy. General path: gather.
// Overwrites the hi/lo scratch region with the final merged output.
// ---------------------------------------------------------------------------
__global__ void k_merge(const float* __restrict__ tok, const float* __restrict__ ws_w,
                        const int* __restrict__ ws_flag, const int* __restrict__ ws_gids,
                        float* __restrict__ out) {
    int b = blockIdx.y;
    int idx4 = blockIdx.x * 256 + threadIdx.x;     // < 37632 = cND/4
    int n = idx4 / 192, d4 = idx4 - n * 192;
    size_t e = (size_t)b * cND + (size_t)n * cD + 4 * d4;
    if (ws_flag[b]) {
        float wv = ws_w[b * cN + n];
        float4 v = *(const float4*)(tok + e);
        v.x *= wv; v.y *= wv; v.z *= wv; v.w *= wv;
        *(float4*)(out + e) = v;
    } else {
        float4 acc = make_float4(0.f, 0.f, 0.f, 0.f);
        const int* g = ws_gids + b * cN;
        const float* wp = ws_w + b * cN;
        const float* tb = tok + (size_t)b * cND + 4 * d4;
        for (int j = 0; j < cN; j++) {
            if (g[j] == n) {
                float4 v = *(const float4*)(tb + (size_t)j * cD);
                float wv = wp[j];
                acc.x += v.x * wv; acc.y += v.y * wv; acc.z += v.z * wv; acc.w += v.w * wv;
            }
        }
        *(float4*)(out + e) = acc;
    }
}

// ---------------------------------------------------------------------------
extern "C" void kernel_launch(void* const* d_in, const int* in_sizes, int n_in,
                              void* d_out, int out_size, void* d_ws, size_t ws_size,
                              hipStream_t stream) {
    const float* tok = (const float*)d_in[0];
    const float* mo  = (const float*)d_in[1];
    const float* sa  = (const float*)d_in[2];
    // d_in[3] (compression_ratio) has coefficient (1-0.5-0.5)==0 in the ref.

    float* out = (float*)d_out;
    float* out_merged = out;                                  // B*N*D
    float* out_sim    = out + cBND;                           // B*N*N
    float* out_imp    = out_sim + (size_t)cB * cNN;           // B*N
    float* out_gids   = out_imp + (size_t)cB * cN;            // B*N (as float)

    // bf16 hi/lo planes live in the merged region (exactly B*N*D*4 bytes)
    unsigned short* planes = (unsigned short*)out_merged;

    float* wsf     = (float*)d_ws;
    float* ws_max  = wsf;                   // 2 floats
    float* ws_imp  = wsf + 64;              // B*N
    float* ws_w    = ws_imp + cB * cN;      // B*N
    int*   ws_flag = (int*)(ws_w + cB * cN);// B ints
    int*   ws_gids = ws_flag + cB;          // B*N ints

    k_maxes<<<1, 1024, 0, stream>>>(mo, sa, ws_max);
    k_importance<<<cB, 256, 0, stream>>>(mo, sa, ws_max, out_imp, ws_imp);
    k_convert<<<(cB * cN + 3) / 4, 256, 0, stream>>>(tok, planes);
    k_sim<<<512, 256, 0, stream>>>(planes, out_sim);
    k_group<<<cB, 256, 0, stream>>>(out_sim, ws_imp, out_gids, ws_w, ws_flag, ws_gids);
    k_merge<<<dim3(147, cB), 256, 0, stream>>>(tok, ws_w, ws_flag, ws_gids, out_merged);
}

// Round 3
// 285.589 us; speedup vs baseline: 1.6269x; 1.0347x over previous
//
#include <hip/hip_runtime.h>
#include <cstdint>

static constexpr int cB = 128;
static constexpr int cN = 196;
static constexpr int cD = 768;
static constexpr int cNN = cN * cN;      // 38416
static constexpr int cND = cN * cD;      // 150528
static constexpr float cEPS = 1e-6f;
static constexpr size_t cBND = (size_t)cB * cN * cD;   // 19,267,584 elements

typedef __attribute__((ext_vector_type(8))) short short8;
typedef __attribute__((ext_vector_type(4))) float f32x4;

__device__ __forceinline__ unsigned short bf16_rne(float x) {
    unsigned u = __builtin_bit_cast(unsigned, x);
    u += 0x7FFFu + ((u >> 16) & 1u);
    return (unsigned short)(u >> 16);
}

// ---------------------------------------------------------------------------
// K1: fused global-max + per-batch importance. One block per batch; every
// block redundantly computes the global max of mo/sa (200 KB, L2-absorbed).
// Also writes w = imp/(imp+eps) (the fast-path merge weight).
// ---------------------------------------------------------------------------
__global__ __launch_bounds__(256) void k_imp(const float* __restrict__ mo,
                                             const float* __restrict__ sa,
                                             float* __restrict__ out_imp,
                                             float* __restrict__ ws_imp,
                                             float* __restrict__ ws_w) {
    int b = blockIdx.x, t = threadIdx.x;
    __shared__ float redm[4], reds[4], lo_s[4], hi_s[4], MS[2], LOHI[2];
    // global max (values are uniform(0,1), so 0 is a safe identity)
    float mm = 0.f, ms = 0.f;
    for (int i = t; i < cB * cN; i += 256) {
        mm = fmaxf(mm, mo[i]);
        ms = fmaxf(ms, sa[i]);
    }
    #pragma unroll
    for (int off = 32; off; off >>= 1) {
        mm = fmaxf(mm, __shfl_down(mm, off));
        ms = fmaxf(ms, __shfl_down(ms, off));
    }
    if ((t & 63) == 0) { redm[t >> 6] = mm; reds[t >> 6] = ms; }
    __syncthreads();
    if (t == 0) {
        float a = redm[0], c = reds[0];
        for (int w = 1; w < 4; w++) { a = fmaxf(a, redm[w]); c = fmaxf(c, reds[w]); }
        MS[0] = 1.0f / (a + cEPS);
        MS[1] = 1.0f / (c + cEPS);
    }
    __syncthreads();
    float Minv = MS[0], Sinv = MS[1];
    float v = 0.f, lo = 1e30f, hi = -1e30f;
    if (t < cN) {
        v = 0.5f * mo[b * cN + t] * Minv + 0.5f * sa[b * cN + t] * Sinv;
        lo = v; hi = v;
    }
    #pragma unroll
    for (int off = 32; off; off >>= 1) {
        lo = fminf(lo, __shfl_down(lo, off));
        hi = fmaxf(hi, __shfl_down(hi, off));
    }
    if ((t & 63) == 0) { lo_s[t >> 6] = lo; hi_s[t >> 6] = hi; }
    __syncthreads();
    if (t == 0) {
        float l = lo_s[0], h = hi_s[0];
        for (int w = 1; w < 4; w++) { l = fminf(l, lo_s[w]); h = fmaxf(h, hi_s[w]); }
        LOHI[0] = l; LOHI[1] = h;
    }
    __syncthreads();
    if (t < cN) {
        float imp = (v - LOHI[0]) / (LOHI[1] - LOHI[0] + cEPS);
        out_imp[b * cN + t] = imp;
        ws_imp[b * cN + t] = imp;
        ws_w[b * cN + t] = imp / (imp + cEPS);
    }
}

// ---------------------------------------------------------------------------
// K2: per-token normalize -> bf16 hi plane; optionally also writes the
// fast-path merged output (tok * w) in the same pass (one tok read total).
// One wave per token, 12 elements/lane.
// ---------------------------------------------------------------------------
__global__ __launch_bounds__(256) void k_prep(const float* __restrict__ tok,
                                              const float* __restrict__ ws_w,
                                              unsigned short* __restrict__ plane,
                                              float* __restrict__ merged,
                                              int write_merged) {
    int wid = blockIdx.x * 4 + (threadIdx.x >> 6);   // token index
    int lane = threadIdx.x & 63;
    if (wid >= cB * cN) return;
    const float4* p4 = (const float4*)(tok + (size_t)wid * cD);  // 192 float4s
    float4 v[3];
    float s = 0.f;
    #pragma unroll
    for (int r = 0; r < 3; r++) {
        v[r] = p4[lane + 64 * r];
        s += v[r].x * v[r].x + v[r].y * v[r].y + v[r].z * v[r].z + v[r].w * v[r].w;
    }
    #pragma unroll
    for (int off = 32; off; off >>= 1) s += __shfl_xor(s, off);
    float inv = 1.0f / fmaxf(sqrtf(s), 1e-12f);
    float w = ws_w[wid];
    ushort4* hp = (ushort4*)(plane + (size_t)wid * cD);
    float4* mp = (float4*)(merged + (size_t)wid * cD);
    #pragma unroll
    for (int r = 0; r < 3; r++) {
        ushort4 h;
        h.x = bf16_rne(v[r].x * inv);
        h.y = bf16_rne(v[r].y * inv);
        h.z = bf16_rne(v[r].z * inv);
        h.w = bf16_rne(v[r].w * inv);
        hp[lane + 64 * r] = h;
        if (write_merged) {
            float4 m = v[r];
            m.x *= w; m.y *= w; m.z *= w; m.w *= w;
            mp[lane + 64 * r] = m;
        }
    }
}

// ---------------------------------------------------------------------------
// K3: sim = tn . tn^T per batch, bf16 MFMA. 128x128 tile/block; 4 waves in a
// 2x2 arrangement, each computing 64x64 (4x4 fragments) -> per K-chunk per
// wave: 8 ds_read_b128 + 16 mfma_f32_16x16x32_bf16. LDS row stride 40 bf16
// (80 B) keeps frag reads at free 2-way bank aliasing. XCD-swizzled grid.
// ---------------------------------------------------------------------------
__global__ __launch_bounds__(256, 2) void k_sim(const unsigned short* __restrict__ plane,
                                                float* __restrict__ out_sim) {
    __shared__ unsigned short sA[128 * 40];
    __shared__ unsigned short sB[128 * 40];

    int bid = blockIdx.x;            // 0..511
    int xcd = bid & 7;
    int lin = bid >> 3;              // 0..63
    int b   = xcd + 8 * (lin >> 2);  // all 4 tiles of a batch -> same XCD
    int tile = lin & 3;
    int rb = (tile >> 1) * 128, cb = (tile & 1) * 128;

    int t = threadIdx.x;
    int w = t >> 6, lane = t & 63;
    int lr = lane & 15, kf = (lane >> 4) * 8;    // frag row/col and k-offset
    int wr = (w >> 1) * 64, wc = (w & 1) * 64;   // wave sub-tile origin

    f32x4 acc[4][4];
    #pragma unroll
    for (int i = 0; i < 4; i++)
        #pragma unroll
        for (int j = 0; j < 4; j++) acc[i][j] = (f32x4){0.f, 0.f, 0.f, 0.f};

    const size_t bN = (size_t)b * cN;
    int srow = t >> 2;          // staging rows 0..63 (+64 on second pass)
    int q = t & 3;              // 16B quarter of a 64B row-chunk

    for (int k0 = 0; k0 < cD; k0 += 32) {
        #pragma unroll
        for (int p = 0; p < 2; ++p) {
            int row = srow + 64 * p;
            size_t koff = (size_t)k0 + 8 * q;
            uint4 va = make_uint4(0u, 0u, 0u, 0u), vb = va;
            int gr = rb + row;
            if (gr < cN) va = *(const uint4*)(plane + (bN + gr) * cD + koff);
            int gc = cb + row;
            if (gc < cN) vb = *(const uint4*)(plane + (bN + gc) * cD + koff);
            *(uint4*)&sA[row * 40 + 8 * q] = va;
            *(uint4*)&sB[row * 40 + 8 * q] = vb;
        }
        __syncthreads();

        short8 af[4], bf[4];
        #pragma unroll
        for (int rg = 0; rg < 4; rg++)
            af[rg] = *(const short8*)&sA[(wr + 16 * rg + lr) * 40 + kf];
        #pragma unroll
        for (int cg = 0; cg < 4; cg++)
            bf[cg] = *(const short8*)&sB[(wc + 16 * cg + lr) * 40 + kf];
        #pragma unroll
        for (int rg = 0; rg < 4; rg++)
            #pragma unroll
            for (int cg = 0; cg < 4; cg++)
                acc[rg][cg] = __builtin_amdgcn_mfma_f32_16x16x32_bf16(af[rg], bf[cg], acc[rg][cg], 0, 0, 0);
        __syncthreads();
    }

    // epilogue: C/D layout col=lane&15, row=(lane>>4)*4+reg
    float* so = out_sim + (size_t)b * cNN;
    #pragma unroll
    for (int rg = 0; rg < 4; rg++) {
        int Rbase = rb + wr + 16 * rg + (lane >> 4) * 4;
        #pragma unroll
        for (int cg = 0; cg < 4; cg++) {
            int C = cb + wc + 16 * cg + lr;
            if (C >= cN) continue;
            #pragma unroll
            for (int i = 0; i < 4; i++) {
                int R = Rbase + i;
                if (R < cN) so[(size_t)R * cN + C] = (R == C) ? 0.f : acc[rg][cg][i];
            }
        }
    }
}

// ---------------------------------------------------------------------------
// K4: grouping. One block per batch; fast path when no edges (always, for
// random tokens: cos-sim sigma ~0.036 << 0.9). General path = faithful
// sequential-root BFS; if merged_mode==1 (merged was prewritten with the
// fast-path values) it also rewrites merged in-block for edge batches.
// ---------------------------------------------------------------------------
__global__ __launch_bounds__(256) void k_group(const float* __restrict__ sim,
                                               const float* __restrict__ ws_imp,
                                               const float* __restrict__ tok,
                                               float* __restrict__ out_gids,
                                               float* __restrict__ ws_w,
                                               int* __restrict__ ws_flag,
                                               int* __restrict__ ws_gids,
                                               float* __restrict__ merged,
                                               int merged_mode) {
    int b = blockIdx.x, t = threadIdx.x;
    __shared__ float impL[cN];
    __shared__ unsigned long long reachw[4], assignedw[4], edge_s[4];
    __shared__ int flag;
    __shared__ int gidsL[cN];
    __shared__ float denomL[cN];
    __shared__ float wL[cN];

    if (t < cN) impL[t] = ws_imp[b * cN + t];
    __syncthreads();

    unsigned long long m0 = 0, m1 = 0, m2 = 0, m3 = 0;
    if (t < cN) {
        const float* srow = sim + (size_t)b * cNN;
        for (int n = 0; n < cN; n++) {
            float sv = srow[(size_t)n * cN + t];   // coalesced across t
            if (sv > 0.9f && impL[n] < 0.5f) {
                if (n < 64)       m0 |= 1ull << n;
                else if (n < 128) m1 |= 1ull << (n - 64);
                else if (n < 192) m2 |= 1ull << (n - 128);
                else              m3 |= 1ull << (n - 192);
            }
        }
    }
    unsigned long long anym = m0 | m1 | m2 | m3;
    unsigned long long bal = __ballot(anym != 0ull);
    if ((t & 63) == 0) edge_s[t >> 6] = bal;
    __syncthreads();
    bool has_edges = (edge_s[0] | edge_s[1] | edge_s[2] | edge_s[3]) != 0ull;

    if (!has_edges) {
        if (t < cN) {
            float imp = impL[t];
            ws_w[b * cN + t] = imp / (imp + cEPS);
            ws_gids[b * cN + t] = t;
            out_gids[b * cN + t] = (float)t;
        }
        if (t == 0) ws_flag[b] = 1;
        return;   // merged (mode 1) already holds tok*w — correct
    }

    // ---- general sequential-root BFS (faithful to reference) ----
    if (t < 4) assignedw[t] = 0ull;
    if (t < cN) { gidsL[t] = 0; denomL[t] = 0.f; }
    __syncthreads();
    int gid = 0;
    int wrd_t = t >> 6, bit_t = t & 63;
    for (int r = 0; r < cN; r++) {
        if ((assignedw[r >> 6] >> (r & 63)) & 1ull) continue;   // uniform
        if (t < 4) reachw[t] = (t == (r >> 6)) ? (1ull << (r & 63)) : 0ull;
        __syncthreads();
        int changed = 1;
        while (changed) {
            unsigned long long hit = (m0 & reachw[0]) | (m1 & reachw[1]) |
                                     (m2 & reachw[2]) | (m3 & reachw[3]);
            bool inre = (t < cN) && ((reachw[wrd_t] >> bit_t) & 1ull);
            bool unass = (t < cN) && !((assignedw[wrd_t] >> bit_t) & 1ull);
            bool p = inre || (hit != 0ull && unass);
            unsigned long long nw = __ballot(p);
            __syncthreads();
            if (t == 0) flag = 0;
            __syncthreads();
            if ((t & 63) == 0) {
                if (nw != reachw[t >> 6]) flag = 1;
                reachw[t >> 6] = nw;
            }
            __syncthreads();
            changed = flag;
        }
        if ((t < cN) && ((reachw[wrd_t] >> bit_t) & 1ull)) gidsL[t] = gid;
        if (t < 4) assignedw[t] |= reachw[t];
        gid++;
        __syncthreads();
    }
    if (t < cN) atomicAdd(&denomL[gidsL[t]], impL[t]);
    __syncthreads();
    if (t < cN) {
        int g = gidsL[t];
        float wv = impL[t] / (denomL[g] + cEPS);
        ws_w[b * cN + t] = wv;
        wL[t] = wv;
        ws_gids[b * cN + t] = g;
        out_gids[b * cN + t] = (float)g;
    }
    if (t == 0) ws_flag[b] = 0;
    __syncthreads();

    if (merged_mode == 1) {
        // merged was prewritten assuming identity grouping — rewrite it.
        // (cold path: never taken for random tokens; correctness only)
        if (t < 192) {
            for (int n = 0; n < cN; n++) {
                float4 acc = make_float4(0.f, 0.f, 0.f, 0.f);
                for (int j = 0; j < cN; j++) {
                    if (gidsL[j] == n) {
                        const float4 v = *(const float4*)(tok + (size_t)b * cND + (size_t)j * cD + 4 * t);
                        float wv = wL[j];
                        acc.x += v.x * wv; acc.y += v.y * wv;
                        acc.z += v.z * wv; acc.w += v.w * wv;
                    }
                }
                *(float4*)(merged + (size_t)b * cND + (size_t)n * cD + 4 * t) = acc;
            }
        }
    }
}

// ---------------------------------------------------------------------------
// K5 (fallback path only, when ws is too small to host the plane): merged
// from tok with flags/gids. Fast path: scaled copy; general: gather.
// ---------------------------------------------------------------------------
__global__ void k_merge(const float* __restrict__ tok, const float* __restrict__ ws_w,
                        const int* __restrict__ ws_flag, const int* __restrict__ ws_gids,
                        float* __restrict__ out) {
    int b = blockIdx.y;
    int idx4 = blockIdx.x * 256 + threadIdx.x;     // < 37632 = cND/4
    int n = idx4 / 192, d4 = idx4 - n * 192;
    size_t e = (size_t)b * cND + (size_t)n * cD + 4 * d4;
    if (ws_flag[b]) {
        float wv = ws_w[b * cN + n];
        float4 v = *(const float4*)(tok + e);
        v.x *= wv; v.y *= wv; v.z *= wv; v.w *= wv;
        *(float4*)(out + e) = v;
    } else {
        float4 acc = make_float4(0.f, 0.f, 0.f, 0.f);
        const int* g = ws_gids + b * cN;
        const float* wp = ws_w + b * cN;
        const float* tb = tok + (size_t)b * cND + 4 * d4;
        for (int j = 0; j < cN; j++) {
            if (g[j] == n) {
                float4 v = *(const float4*)(tb + (size_t)j * cD);
                float wv = wp[j];
                acc.x += v.x * wv; acc.y += v.y * wv; acc.z += v.z * wv; acc.w += v.w * wv;
            }
        }
        *(float4*)(out + e) = acc;
    }
}

// ---------------------------------------------------------------------------
extern "C" void kernel_launch(void* const* d_in, const int* in_sizes, int n_in,
                              void* d_out, int out_size, void* d_ws, size_t ws_size,
                              hipStream_t stream) {
    const float* tok = (const float*)d_in[0];
    const float* mo  = (const float*)d_in[1];
    const float* sa  = (const float*)d_in[2];
    // d_in[3] (compression_ratio) has coefficient (1-0.5-0.5)==0 in the ref.

    float* out = (float*)d_out;
    float* out_merged = out;                                  // B*N*D
    float* out_sim    = out + cBND;                           // B*N*N
    float* out_imp    = out_sim + (size_t)cB * cNN;           // B*N
    float* out_gids   = out_imp + (size_t)cB * cN;            // B*N (as float)

    float* wsf     = (float*)d_ws;
    float* ws_imp  = wsf;                        // B*N
    float* ws_w    = ws_imp + cB * cN;           // B*N
    int*   ws_flag = (int*)(ws_w + cB * cN);     // B ints
    int*   ws_gids = ws_flag + cB;               // B*N ints

    const size_t plane_off = 1u << 19;           // 512 KB
    const size_t need = plane_off + cBND * sizeof(unsigned short);
    const bool pathA = ws_size >= need;          // constant across calls

    unsigned short* plane = pathA
        ? (unsigned short*)((char*)d_ws + plane_off)
        : (unsigned short*)out_merged;           // fallback: plane in merged region

    k_imp<<<cB, 256, 0, stream>>>(mo, sa, out_imp, ws_imp, ws_w);
    k_prep<<<(cB * cN + 3) / 4, 256, 0, stream>>>(tok, ws_w, plane, out_merged,
                                                  pathA ? 1 : 0);
    k_sim<<<512, 256, 0, stream>>>(plane, out_sim);
    k_group<<<cB, 256, 0, stream>>>(out_sim, ws_imp, tok, out_gids, ws_w,
                                    ws_flag, ws_gids, out_merged, pathA ? 1 : 0);
    if (!pathA)
        k_merge<<<dim3(147, cB), 256, 0, stream>>>(tok, ws_w, ws_flag, ws_gids, out_merged);
}

// Round 4
// 240.417 us; speedup vs baseline: 1.9326x; 1.1879x over previous
//
#include <hip/hip_runtime.h>
#include <cstdint>

static constexpr int cB = 128;
static constexpr int cN = 196;
static constexpr int cD = 768;
static constexpr int cNN = cN * cN;      // 38416
static constexpr int cND = cN * cD;      // 150528
static constexpr float cEPS = 1e-6f;
static constexpr size_t cBND = (size_t)cB * cN * cD;   // 19,267,584 elements

typedef __attribute__((ext_vector_type(8))) short short8;
typedef __attribute__((ext_vector_type(4))) float f32x4;
typedef unsigned long long u64;

__device__ __forceinline__ unsigned short bf16_rne(float x) {
    unsigned u = __builtin_bit_cast(unsigned, x);
    u += 0x7FFFu + ((u >> 16) & 1u);
    return (unsigned short)(u >> 16);
}

// ---------------------------------------------------------------------------
// K1: fused global-max + per-batch importance; also zero-inits ws_adj.
// One block per batch; every block redundantly computes the global max of
// mo/sa (200 KB, L2-absorbed). Writes w = imp/(imp+eps) fast-path weight.
// ---------------------------------------------------------------------------
__global__ __launch_bounds__(256) void k_imp(const float* __restrict__ mo,
                                             const float* __restrict__ sa,
                                             float* __restrict__ out_imp,
                                             float* __restrict__ ws_imp,
                                             float* __restrict__ ws_w,
                                             u64* __restrict__ ws_adj) {
    int b = blockIdx.x, t = threadIdx.x;
    __shared__ float redm[4], reds[4], lo_s[4], hi_s[4], MS[2], LOHI[2];

    // zero the adjacency mask table (poisoned 0xAA before every call)
    for (int i = b * 256 + t; i < cB * cN * 4; i += cB * 256) ws_adj[i] = 0ull;

    float mm = 0.f, ms = 0.f;   // inputs are uniform(0,1): 0 is a safe identity
    for (int i = t; i < cB * cN; i += 256) {
        mm = fmaxf(mm, mo[i]);
        ms = fmaxf(ms, sa[i]);
    }
    #pragma unroll
    for (int off = 32; off; off >>= 1) {
        mm = fmaxf(mm, __shfl_down(mm, off));
        ms = fmaxf(ms, __shfl_down(ms, off));
    }
    if ((t & 63) == 0) { redm[t >> 6] = mm; reds[t >> 6] = ms; }
    __syncthreads();
    if (t == 0) {
        float a = redm[0], c = reds[0];
        for (int w = 1; w < 4; w++) { a = fmaxf(a, redm[w]); c = fmaxf(c, reds[w]); }
        MS[0] = 1.0f / (a + cEPS);
        MS[1] = 1.0f / (c + cEPS);
    }
    __syncthreads();
    float Minv = MS[0], Sinv = MS[1];
    float v = 0.f, lo = 1e30f, hi = -1e30f;
    if (t < cN) {
        v = 0.5f * mo[b * cN + t] * Minv + 0.5f * sa[b * cN + t] * Sinv;
        lo = v; hi = v;
    }
    #pragma unroll
    for (int off = 32; off; off >>= 1) {
        lo = fminf(lo, __shfl_down(lo, off));
        hi = fmaxf(hi, __shfl_down(hi, off));
    }
    if ((t & 63) == 0) { lo_s[t >> 6] = lo; hi_s[t >> 6] = hi; }
    __syncthreads();
    if (t == 0) {
        float l = lo_s[0], h = hi_s[0];
        for (int w = 1; w < 4; w++) { l = fminf(l, lo_s[w]); h = fmaxf(h, hi_s[w]); }
        LOHI[0] = l; LOHI[1] = h;
    }
    __syncthreads();
    if (t < cN) {
        float imp = (v - LOHI[0]) / (LOHI[1] - LOHI[0] + cEPS);
        out_imp[b * cN + t] = imp;
        ws_imp[b * cN + t] = imp;
        ws_w[b * cN + t] = imp / (imp + cEPS);
    }
}

// ---------------------------------------------------------------------------
// K2: per-token pass over tok: bf16(raw) plane + inv-norm + (fast-path)
// merged = tok*w. One wave per token, 12 elements/lane, one tok read total.
// Normalization is NOT applied to the plane — k_sim scales by invn in its
// epilogue (bf16 relative error is scale-invariant).
// ---------------------------------------------------------------------------
__global__ __launch_bounds__(256) void k_prep(const float* __restrict__ tok,
                                              const float* __restrict__ ws_w,
                                              unsigned short* __restrict__ plane,
                                              float* __restrict__ ws_invn,
                                              float* __restrict__ merged,
                                              int write_merged) {
    int wid = blockIdx.x * 4 + (threadIdx.x >> 6);   // token index
    int lane = threadIdx.x & 63;
    if (wid >= cB * cN) return;
    const float4* p4 = (const float4*)(tok + (size_t)wid * cD);  // 192 float4s
    float4 v[3];
    float s = 0.f;
    #pragma unroll
    for (int r = 0; r < 3; r++) {
        v[r] = p4[lane + 64 * r];
        s += v[r].x * v[r].x + v[r].y * v[r].y + v[r].z * v[r].z + v[r].w * v[r].w;
    }
    #pragma unroll
    for (int off = 32; off; off >>= 1) s += __shfl_xor(s, off);
    if (lane == 0) ws_invn[wid] = 1.0f / fmaxf(sqrtf(s), 1e-12f);
    float w = ws_w[wid];
    ushort4* hp = (ushort4*)(plane + (size_t)wid * cD);
    float4* mp = (float4*)(merged + (size_t)wid * cD);
    #pragma unroll
    for (int r = 0; r < 3; r++) {
        ushort4 h;
        h.x = bf16_rne(v[r].x);
        h.y = bf16_rne(v[r].y);
        h.z = bf16_rne(v[r].z);
        h.w = bf16_rne(v[r].w);
        hp[lane + 64 * r] = h;
        if (write_merged) {
            float4 m = v[r];
            m.x *= w; m.y *= w; m.z *= w; m.w *= w;
            mp[lane + 64 * r] = m;
        }
    }
}

// ---------------------------------------------------------------------------
// K3: sim = (tok.tok^T)*invnR*invnC per batch, bf16 MFMA, 128x128 tile/block,
// 4 waves 2x2 (64x64 each): per K-chunk per wave 8 ds_read_b128 + 16 MFMA.
// LDS row stride 40 bf16 keeps frag reads at free 2-way bank aliasing.
// Epilogue also emits the directed-edge masks (sim>0.9 && imp[row]<0.5) into
// ws_adj (per-(b,col) 4x64-bit incoming-edge bitmask) — never fires for
// random tokens, so the atomics are predicated off. XCD-swizzled grid.
// ---------------------------------------------------------------------------
__global__ __launch_bounds__(256, 2) void k_sim(const unsigned short* __restrict__ plane,
                                                const float* __restrict__ ws_invn,
                                                const float* __restrict__ ws_imp,
                                                float* __restrict__ out_sim,
                                                u64* __restrict__ ws_adj) {
    __shared__ unsigned short sA[128 * 40];
    __shared__ unsigned short sB[128 * 40];
    __shared__ float invR[128], invC[128], impR[128];
    __shared__ u64 ldsAdj[256];          // [col 0..127][word 0..1]

    int bid = blockIdx.x;            // 0..511
    int xcd = bid & 7;
    int lin = bid >> 3;              // 0..63
    int b   = xcd + 8 * (lin >> 2);  // all 4 tiles of a batch -> same XCD
    int tile = lin & 3;
    int rb = (tile >> 1) * 128, cb = (tile & 1) * 128;

    int t = threadIdx.x;
    int w = t >> 6, lane = t & 63;
    int lr = lane & 15, kf = (lane >> 4) * 8;    // frag row/col and k-offset
    int wr = (w >> 1) * 64, wc = (w & 1) * 64;   // wave sub-tile origin

    const size_t bN = (size_t)b * cN;

    ldsAdj[t] = 0ull;
    if (t < 128) {
        int gr = rb + t;
        invR[t] = (gr < cN) ? ws_invn[bN + gr] : 0.f;
        impR[t] = (gr < cN) ? ws_imp[bN + gr] : 1.f;
    } else {
        int gc = cb + (t - 128);
        invC[t - 128] = (gc < cN) ? ws_invn[bN + gc] : 0.f;
    }

    f32x4 acc[4][4];
    #pragma unroll
    for (int i = 0; i < 4; i++)
        #pragma unroll
        for (int j = 0; j < 4; j++) acc[i][j] = (f32x4){0.f, 0.f, 0.f, 0.f};

    int srow = t >> 2;          // staging rows 0..63 (+64 on second pass)
    int q = t & 3;              // 16B quarter of a 64B row-chunk

    for (int k0 = 0; k0 < cD; k0 += 32) {
        #pragma unroll
        for (int p = 0; p < 2; ++p) {
            int row = srow + 64 * p;
            size_t koff = (size_t)k0 + 8 * q;
            uint4 va = make_uint4(0u, 0u, 0u, 0u), vb = va;
            int gr = rb + row;
            if (gr < cN) va = *(const uint4*)(plane + (bN + gr) * cD + koff);
            int gc = cb + row;
            if (gc < cN) vb = *(const uint4*)(plane + (bN + gc) * cD + koff);
            *(uint4*)&sA[row * 40 + 8 * q] = va;
            *(uint4*)&sB[row * 40 + 8 * q] = vb;
        }
        __syncthreads();

        short8 af[4], bf[4];
        #pragma unroll
        for (int rg = 0; rg < 4; rg++)
            af[rg] = *(const short8*)&sA[(wr + 16 * rg + lr) * 40 + kf];
        #pragma unroll
        for (int cg = 0; cg < 4; cg++)
            bf[cg] = *(const short8*)&sB[(wc + 16 * cg + lr) * 40 + kf];
        #pragma unroll
        for (int rg = 0; rg < 4; rg++)
            #pragma unroll
            for (int cg = 0; cg < 4; cg++)
                acc[rg][cg] = __builtin_amdgcn_mfma_f32_16x16x32_bf16(af[rg], bf[cg], acc[rg][cg], 0, 0, 0);
        __syncthreads();
    }

    // ---- epilogue: C/D layout col=lane&15, row=(lane>>4)*4+reg ----
    float* so = out_sim + (size_t)b * cNN;
    int wloc = w >> 1;                    // local 64-row word this wave covers
    #pragma unroll
    for (int rg = 0; rg < 4; rg++) {
        int rBaseLoc = wr + 16 * rg + (lane >> 4) * 4;
        #pragma unroll
        for (int cg = 0; cg < 4; cg++) {
            int cLoc = wc + 16 * cg + lr;
            int C = cb + cLoc;
            if (C >= cN) continue;
            float ic = invC[cLoc];
            u64 bits = 0ull;
            #pragma unroll
            for (int i = 0; i < 4; i++) {
                int rLoc = rBaseLoc + i;
                int R = rb + rLoc;
                if (R >= cN) continue;
                float val = (R == C) ? 0.f : acc[rg][cg][i] * invR[rLoc] * ic;
                so[(size_t)R * cN + C] = val;
                if (val > 0.9f && impR[rLoc] < 0.5f) bits |= 1ull << (R & 63);
            }
            if (bits) atomicOr(&ldsAdj[cLoc * 2 + wloc], bits);   // cold
        }
    }
    __syncthreads();
    // flush nonzero mask words to global (zero atomics in practice)
    {
        int cLoc = t >> 1, wl = t & 1;
        int C = cb + cLoc;
        u64 v = ldsAdj[t];
        if (C < cN && v)
            atomicOr(&ws_adj[((size_t)b * cN + C) * 4 + (rb >> 6) + wl], v);
    }
}

// ---------------------------------------------------------------------------
// K4: grouping from the precomputed masks (32 B/thread). Fast path when no
// edges (always, for random tokens: cos-sim sigma ~0.036 << 0.9). General
// path = faithful sequential-root BFS; if merged_mode==1 it also rewrites
// merged in-block for edge batches.
// ---------------------------------------------------------------------------
__global__ __launch_bounds__(256) void k_group(const u64* __restrict__ ws_adj,
                                               const float* __restrict__ ws_imp,
                                               const float* __restrict__ tok,
                                               float* __restrict__ out_gids,
                                               float* __restrict__ ws_w,
                                               int* __restrict__ ws_flag,
                                               int* __restrict__ ws_gids,
                                               float* __restrict__ merged,
                                               int merged_mode) {
    int b = blockIdx.x, t = threadIdx.x;
    __shared__ float impL[cN];
    __shared__ u64 reachw[4], assignedw[4], edge_s[4];
    __shared__ int flag;
    __shared__ int gidsL[cN];
    __shared__ float denomL[cN];
    __shared__ float wL[cN];

    u64 m0 = 0, m1 = 0, m2 = 0, m3 = 0;
    if (t < cN) {
        impL[t] = ws_imp[b * cN + t];
        const u64* ap = ws_adj + ((size_t)b * cN + t) * 4;
        m0 = ap[0]; m1 = ap[1]; m2 = ap[2]; m3 = ap[3];
    }
    u64 anym = m0 | m1 | m2 | m3;
    u64 bal = __ballot(anym != 0ull);
    if ((t & 63) == 0) edge_s[t >> 6] = bal;
    __syncthreads();
    bool has_edges = (edge_s[0] | edge_s[1] | edge_s[2] | edge_s[3]) != 0ull;

    if (!has_edges) {
        if (t < cN) {
            float imp = impL[t];
            ws_w[b * cN + t] = imp / (imp + cEPS);
            ws_gids[b * cN + t] = t;
            out_gids[b * cN + t] = (float)t;
        }
        if (t == 0) ws_flag[b] = 1;
        return;   // merged (mode 1) already holds tok*w — correct
    }

    // ---- general sequential-root BFS (faithful to reference) ----
    if (t < 4) assignedw[t] = 0ull;
    if (t < cN) { gidsL[t] = 0; denomL[t] = 0.f; }
    __syncthreads();
    int gid = 0;
    int wrd_t = t >> 6, bit_t = t & 63;
    for (int r = 0; r < cN; r++) {
        if ((assignedw[r >> 6] >> (r & 63)) & 1ull) continue;   // uniform
        if (t < 4) reachw[t] = (t == (r >> 6)) ? (1ull << (r & 63)) : 0ull;
        __syncthreads();
        int changed = 1;
        while (changed) {
            u64 hit = (m0 & reachw[0]) | (m1 & reachw[1]) |
                      (m2 & reachw[2]) | (m3 & reachw[3]);
            bool inre = (t < cN) && ((reachw[wrd_t] >> bit_t) & 1ull);
            bool unass = (t < cN) && !((assignedw[wrd_t] >> bit_t) & 1ull);
            bool p = inre || (hit != 0ull && unass);
            u64 nw = __ballot(p);
            __syncthreads();
            if (t == 0) flag = 0;
            __syncthreads();
            if ((t & 63) == 0) {
                if (nw != reachw[t >> 6]) flag = 1;
                reachw[t >> 6] = nw;
            }
            __syncthreads();
            changed = flag;
        }
        if ((t < cN) && ((reachw[wrd_t] >> bit_t) & 1ull)) gidsL[t] = gid;
        if (t < 4) assignedw[t] |= reachw[t];
        gid++;
        __syncthreads();
    }
    if (t < cN) atomicAdd(&denomL[gidsL[t]], impL[t]);
    __syncthreads();
    if (t < cN) {
        int g = gidsL[t];
        float wv = impL[t] / (denomL[g] + cEPS);
        ws_w[b * cN + t] = wv;
        wL[t] = wv;
        ws_gids[b * cN + t] = g;
        out_gids[b * cN + t] = (float)g;
    }
    if (t == 0) ws_flag[b] = 0;
    __syncthreads();

    if (merged_mode == 1) {
        // merged was prewritten assuming identity grouping — rewrite it.
        // (cold path: never taken for random tokens; correctness only)
        if (t < 192) {
            for (int n = 0; n < cN; n++) {
                float4 acc = make_float4(0.f, 0.f, 0.f, 0.f);
                for (int j = 0; j < cN; j++) {
                    if (gidsL[j] == n) {
                        const float4 v = *(const float4*)(tok + (size_t)b * cND + (size_t)j * cD + 4 * t);
                        float wv = wL[j];
                        acc.x += v.x * wv; acc.y += v.y * wv;
                        acc.z += v.z * wv; acc.w += v.w * wv;
                    }
                }
                *(float4*)(merged + (size_t)b * cND + (size_t)n * cD + 4 * t) = acc;
            }
        }
    }
}

// ---------------------------------------------------------------------------
// K5 (fallback path only, when ws cannot host the plane): merged from tok.
// ---------------------------------------------------------------------------
__global__ void k_merge(const float* __restrict__ tok, const float* __restrict__ ws_w,
                        const int* __restrict__ ws_flag, const int* __restrict__ ws_gids,
                        float* __restrict__ out) {
    int b = blockIdx.y;
    int idx4 = blockIdx.x * 256 + threadIdx.x;     // < 37632 = cND/4
    int n = idx4 / 192, d4 = idx4 - n * 192;
    size_t e = (size_t)b * cND + (size_t)n * cD + 4 * d4;
    if (ws_flag[b]) {
        float wv = ws_w[b * cN + n];
        float4 v = *(const float4*)(tok + e);
        v.x *= wv; v.y *= wv; v.z *= wv; v.w *= wv;
        *(float4*)(out + e) = v;
    } else {
        float4 acc = make_float4(0.f, 0.f, 0.f, 0.f);
        const int* g = ws_gids + b * cN;
        const float* wp = ws_w + b * cN;
        const float* tb = tok + (size_t)b * cND + 4 * d4;
        for (int j = 0; j < cN; j++) {
            if (g[j] == n) {
                float4 v = *(const float4*)(tb + (size_t)j * cD);
                float wv = wp[j];
                acc.x += v.x * wv; acc.y += v.y * wv; acc.z += v.z * wv; acc.w += v.w * wv;
            }
        }
        *(float4*)(out + e) = acc;
    }
}

// ---------------------------------------------------------------------------
extern "C" void kernel_launch(void* const* d_in, const int* in_sizes, int n_in,
                              void* d_out, int out_size, void* d_ws, size_t ws_size,
                              hipStream_t stream) {
    const float* tok = (const float*)d_in[0];
    const float* mo  = (const float*)d_in[1];
    const float* sa  = (const float*)d_in[2];
    // d_in[3] (compression_ratio) has coefficient (1-0.5-0.5)==0 in the ref.

    float* out = (float*)d_out;
    float* out_merged = out;                                  // B*N*D
    float* out_sim    = out + cBND;                           // B*N*N
    float* out_imp    = out_sim + (size_t)cB * cNN;           // B*N
    float* out_gids   = out_imp + (size_t)cB * cN;            // B*N (as float)

    u64*   ws_adj  = (u64*)d_ws;                 // B*N*4 u64 = 802,816 B
    float* ws_imp  = (float*)(ws_adj + (size_t)cB * cN * 4);
    float* ws_w    = ws_imp + cB * cN;
    float* ws_invn = ws_w + cB * cN;
    int*   ws_flag = (int*)(ws_invn + cB * cN);  // B ints
    int*   ws_gids = ws_flag + cB;               // B*N ints  (ends ~1.51 MB)

    const size_t plane_off = 2u << 20;           // 2 MB
    const size_t need = plane_off + cBND * sizeof(unsigned short);
    const bool pathA = ws_size >= need;          // constant across calls

    unsigned short* plane = pathA
        ? (unsigned short*)((char*)d_ws + plane_off)
        : (unsigned short*)out_merged;           // fallback: plane in merged region

    k_imp<<<cB, 256, 0, stream>>>(mo, sa, out_imp, ws_imp, ws_w, ws_adj);
    k_prep<<<(cB * cN + 3) / 4, 256, 0, stream>>>(tok, ws_w, plane, ws_invn,
                                                  out_merged, pathA ? 1 : 0);
    k_sim<<<512, 256, 0, stream>>>(plane, ws_invn, ws_imp, out_sim, ws_adj);
    k_group<<<cB, 256, 0, stream>>>(ws_adj, ws_imp, tok, out_gids, ws_w,
                                    ws_flag, ws_gids, out_merged, pathA ? 1 : 0);
    if (!pathA)
        k_merge<<<dim3(147, cB), 256, 0, stream>>>(tok, ws_w, ws_flag, ws_gids, out_merged);
}